// Round 5
// baseline (113.938 us; speedup 1.0000x reference)
//
#include <hip/hip_runtime.h>

// DepthOffset: for each (b, tap j, oy, ox) find argmin_k |sample(j,k) - center|
// sample(j,k) at (oy + 4*(jr-1) + 2*(kr-1), ox + 4*(jc-1) + 2*(kc-1))
// with TWO-stage zero padding:
//   stage 1 (Sp pad, PH=4): tap pos (oy+4*(jr-1), ox+4*(jc-1)) in-bounds else 0
//     (if off-image, ALL allowed candidates tie at |0-center| -> argmin is the
//      FIRST allowed k: kf = 1 for j in {1,7}, 3 for j in {3,5}, else 0)
//   stage 2 (dp pad, SD=2): final sample pos in-bounds else value 0
// masks: taps j=1,7 allow only kc==1; taps j=3,5 allow only kr==1.
// out[b, j,    oy, ox] = (kbest/3 - 1)*2   (off_h)
// out[b, 9+j,  oy, ox] = (kbest%3 - 1)*2   (off_w)
//
// R5: single launch, region-split grid (replaces R4's pad kernel + 2nd launch).
// R3 showed the cost was dual-path waves (78% of waves straddled the border);
// R4 fixed it with a padded staging buffer but paid a pad kernel + launch gap.
// Here border quads simply never share a wave with bulk quads:
//   - blocks [0, BORDER_BLOCKS): border pixels (1 px/thread, exactly 256*237),
//     branchless clamped-load path (unconditional load at clamped address +
//     cndmask zero-select; no exec diamonds). Launched FIRST to hide under bulk.
//   - blocks [BORDER_BLOCKS, +BULK_BLOCKS): bulk quads (4 px/thread,
//     ox in [8,628], oy in [6,473]) -> every stage-1/stage-2 check statically
//     true: pure branch-free float4 loads + argmin + int4 nontemporal stores.

#define BATCH 4
#define IH 480
#define IW 640

// bulk: ox4 in [2,157] (156 quads/row), oy in [6,473] (468 rows)
#define BULK_QUADS (BATCH * 468 * 156)              // 292,032
#define BULK_BLOCKS ((BULK_QUADS + 255) / 256)      // 1141
// border: x-edge ox in {0..7,632..639} (16 cols x 480 rows) = 30,720 px
//         y-edge oy in {0..5,474..479} x ox in [8,631] (12 x 624) = 29,952 px
#define BORDER_PX (BATCH * (16 * 480 + 12 * 624))   // 60,672 = 237*256
#define BORDER_BLOCKS (BORDER_PX / 256)             // 237

typedef int iv4 __attribute__((ext_vector_type(4)));
typedef float fv4 __attribute__((ext_vector_type(4)));

__global__ __launch_bounds__(256) void depth_offset_kernel(
    const float* __restrict__ d, int* __restrict__ out) {
  const size_t plane = (size_t)IH * IW;
  const int bid = blockIdx.x;
  const int tid = threadIdx.x;

  if (bid >= BORDER_BLOCKS) {
    // ---------------- bulk: branch-free 4-px quads ----------------
    int q = (bid - BORDER_BLOCKS) * 256 + tid;
    if (q >= BULK_QUADS) return;
    int ox = 4 * (2 + q % 156);          // [8, 628]
    int r = q / 156;
    int oy = 6 + r % 468;                // [6, 473]
    int b = r / 468;

    const float* __restrict__ db = d + (size_t)b * (IH * IW);
    int* __restrict__ outb = out + (size_t)b * 18 * plane;
    size_t pix = (size_t)oy * IW + ox;

    float cen[4];
    {
      const fv4 c4 = *reinterpret_cast<const fv4*>(db + pix);
      cen[0] = c4.x; cen[1] = c4.y; cen[2] = c4.z; cen[3] = c4.w;
    }
    const float* p = db + (size_t)(oy - 6) * IW + (ox - 8);

    float rows[7][20];
    auto load_row = [&](int i) {
#pragma unroll
      for (int v = 0; v < 5; ++v) {
        const fv4 rr =
            *reinterpret_cast<const fv4*>(p + (size_t)(2 * i) * IW + 4 * v);
        rows[i][4 * v + 0] = rr.x;
        rows[i][4 * v + 1] = rr.y;
        rows[i][4 * v + 2] = rr.z;
        rows[i][4 * v + 3] = rr.w;
      }
    };

    load_row(0);
    load_row(1);
    load_row(2);

#pragma unroll
    for (int jr = 0; jr < 3; ++jr) {
      if (jr == 1) { load_row(3); load_row(4); }
      if (jr == 2) { load_row(5); load_row(6); }
#pragma unroll
      for (int jc = 0; jc < 3; ++jc) {
        const int j = jr * 3 + jc;
        int bks[4];
#pragma unroll
        for (int q4 = 0; q4 < 4; ++q4) {
          float best = __builtin_huge_valf();
          int bk = 0;
#pragma unroll
          for (int k = 0; k < 9; ++k) {
            const int kr = k / 3, kc = k % 3;
            bool allowed = true;
            if (j == 1 || j == 7) allowed = (kc == 1);
            if (j == 3 || j == 5) allowed = (kr == 1);
            if (!allowed) continue;  // masked = +inf, never argmin

            // local col of (q4, jj=2*jc+kc): q4 + 2 + 2*jj  (window base ox-8)
            float diff =
                fabsf(rows[2 * jr + kr][q4 + 2 + 2 * (2 * jc + kc)] - cen[q4]);
            if (diff < best) {  // strict <: first min wins (jnp.argmin)
              best = diff;
              bk = k;
            }
          }
          bks[q4] = bk;
        }
        iv4 oh, ow;
        oh.x = (bks[0] / 3 - 1) * 2; oh.y = (bks[1] / 3 - 1) * 2;
        oh.z = (bks[2] / 3 - 1) * 2; oh.w = (bks[3] / 3 - 1) * 2;
        ow.x = (bks[0] % 3 - 1) * 2; ow.y = (bks[1] % 3 - 1) * 2;
        ow.z = (bks[2] % 3 - 1) * 2; ow.w = (bks[3] % 3 - 1) * 2;
        __builtin_nontemporal_store(
            oh, reinterpret_cast<iv4*>(outb + (size_t)j * plane + pix));
        __builtin_nontemporal_store(
            ow, reinterpret_cast<iv4*>(outb + (size_t)(9 + j) * plane + pix));
      }
    }
  } else {
    // ---------------- border: 1 px/thread, branchless clamped loads ------
    int p = bid * 256 + tid;  // p < 60,672 exactly
    int b, oy, ox;
    if (p < BATCH * 16 * 480) {
      int xe = p & 15;
      ox = (xe < 8) ? xe : 624 + xe;     // {0..7} u {632..639}
      oy = (p >> 4) % 480;
      b = p / (16 * 480);
    } else {
      int qq = p - BATCH * 16 * 480;
      ox = 8 + qq % 624;                 // [8, 631]
      int rr = qq / 624;
      int yy = rr % 12;
      oy = (yy < 6) ? yy : 468 + yy;     // {0..5} u {474..479}
      b = rr / 12;
    }

    const float* __restrict__ db = d + (size_t)b * (IH * IW);
    int* __restrict__ outb = out + (size_t)b * 18 * plane;
    size_t pix = (size_t)oy * IW + ox;

    const float center = db[pix];
    float nb[7][7];
#pragma unroll
    for (int i = 0; i < 7; ++i) {
      int y = oy + 2 * i - 6;
      int yc = min(max(y, 0), IH - 1);
      bool yok = ((unsigned)y < (unsigned)IH);
#pragma unroll
      for (int jj = 0; jj < 7; ++jj) {
        int x = ox + 2 * jj - 6;
        int xc = min(max(x, 0), IW - 1);
        float v = db[yc * IW + xc];  // unconditional load, clamped addr
        nb[i][jj] = (yok & ((unsigned)x < (unsigned)IW)) ? v : 0.0f;
      }
    }

#pragma unroll
    for (int j = 0; j < 9; ++j) {
      const int jr = j / 3, jc = j % 3;
      // stage-1 (tap-level) check
      int Y = oy + 4 * (jr - 1);
      int X = ox + 4 * (jc - 1);
      bool jok = ((unsigned)Y < (unsigned)IH) & ((unsigned)X < (unsigned)IW);
      const int kf = (j == 1 || j == 7) ? 1 : ((j == 3 || j == 5) ? 3 : 0);

      float best = __builtin_huge_valf();
      int bk = 0;
#pragma unroll
      for (int k = 0; k < 9; ++k) {
        const int kr = k / 3, kc = k % 3;
        bool allowed = true;
        if (j == 1 || j == 7) allowed = (kc == 1);
        if (j == 3 || j == 5) allowed = (kr == 1);
        if (!allowed) continue;

        float diff = fabsf(nb[2 * jr + kr][2 * jc + kc] - center);
        if (diff < best) {  // strict <: first min wins
          best = diff;
          bk = k;
        }
      }
      bk = jok ? bk : kf;  // stage-1: all-zero tap -> first allowed k
      __builtin_nontemporal_store((bk / 3 - 1) * 2,
                                  &outb[(size_t)j * plane + pix]);
      __builtin_nontemporal_store((bk % 3 - 1) * 2,
                                  &outb[(size_t)(9 + j) * plane + pix]);
    }
  }
}

extern "C" void kernel_launch(void* const* d_in, const int* in_sizes, int n_in,
                              void* d_out, int out_size, void* d_ws, size_t ws_size,
                              hipStream_t stream) {
  const float* depth = (const float*)d_in[0];
  int* out = (int*)d_out;
  const int grid = BORDER_BLOCKS + BULK_BLOCKS;  // 237 + 1141 = 1378
  depth_offset_kernel<<<grid, 256, 0, stream>>>(depth, out);
}